// Round 9
// baseline (4230.680 us; speedup 1.0000x reference)
//
#include <hip/hip_runtime.h>
#include <hip/hip_fp16.h>
#include <cstdint>
#include <cstddef>

#define NN 100000
#define EE 200000
#define AA 400000
#define DD 128
#define LL 5

typedef __attribute__((ext_vector_type(8))) short short8v;   // 8 bf16 (4 VGPRs)
typedef __attribute__((ext_vector_type(4))) float f4v;       // MFMA acc

__constant__ float c_bf_start[8] = {0.f, 0.f, 3.f, 0.f, 0.f, 0.f, 0.f, 0.f};
__constant__ float c_bf_step[8]  = {0.1f, 0.05f, 0.3f, 0.05f, 0.05f, 0.05f, 0.5f, 0.05f};
__constant__ int   c_bf_cnt[8]   = {20, 20, 30, 20, 20, 20, 20, 20};
__constant__ float c_bf_gam[8]   = {10.f, 1.f, 1.f, 1.f, 1.f, 1.f, 2.f, 1.f};

__device__ inline short f2bf(float v) {
  unsigned u = __float_as_uint(v);
  unsigned r = (u + 0x7fffu + ((u >> 16) & 1u)) >> 16;   // RNE
  return (short)r;
}
__device__ inline float bf2f(short h) { return __uint_as_float(((unsigned)(unsigned short)h) << 16); }
// 2-way split: v = s0 + s1 + O(2^-17 |v|)
__device__ inline void split2(float v, short& s0, short& s1) {
  s0 = f2bf(v);
  float r1 = v - bf2f(s0);
  s1 = f2bf(r1);
}

// ---------------- atom embedding ----------------
__global__ __launch_bounds__(128) void k_atom_embed(
    const int* __restrict__ xa, const float* __restrict__ tab, float* __restrict__ h)
{
  __shared__ int idx[9];
  int n = blockIdx.x, d = threadIdx.x;
  if (d < 9) idx[d] = xa[n * 9 + d];
  __syncthreads();
  float s = 0.f;
#pragma unroll
  for (int f = 0; f < 9; ++f) s += tab[(f * 124 + idx[f]) * DD + d];
  h[(size_t)n * DD + d] = s;
}

// ---------------- prep: W[k][n] -> Wt planes [n][k] bf16 x2 (5 mats per call) ----
__global__ __launch_bounds__(128) void k_prep_w(
    const float* __restrict__ src,
    short* __restrict__ d0, short* __restrict__ d1)
{
  int b = blockIdx.x;            // 5*128
  int l = b >> 7, n = b & 127;
  int k = threadIdx.x;
  float v = src[l * 16384 + k * 128 + n];
  short s0, s1; split2(v, s0, s1);
  d0[l * 16384 + n * 128 + k] = s0;
  d1[l * 16384 + n * 128 + k] = s1;
}

// ---------------- prep: bond B matrix [6][n=128][k=320] bf16 x2 --------------
// k layout: f*32+c (f<8, RBF) | 256+j one-hot f0/f1 | 288+j one-hot f2, 300: const-1
__global__ __launch_bounds__(320) void k_prep_bond(
    const float* __restrict__ bfW,    // [6][8][30][128]
    const float* __restrict__ btab,   // [6][3][12][128]
    const float* __restrict__ bfb,    // [6][8][128]
    short* __restrict__ d0, short* __restrict__ d1)
{
  int b = blockIdx.x;            // 6*128
  int l = b >> 7, n = b & 127;
  int k = threadIdx.x;           // 0..319
  float v = 0.f;
  if (k < 256) {
    int f = k >> 5, c = k & 31;
    if (c < 30) v = bfW[(((size_t)l * 8 + f) * 30 + c) * 128 + n];
  } else if (k < 288) {
    int j = k - 256;
    if (j < 12)       v = btab[(((size_t)l * 3 + 0) * 12 + j) * 128 + n];
    else if (j < 24)  v = btab[(((size_t)l * 3 + 1) * 12 + (j - 12)) * 128 + n];
  } else {
    int j = k - 288;
    if (j < 12)       v = btab[(((size_t)l * 3 + 2) * 12 + j) * 128 + n];
    else if (j == 12) {
      for (int f = 0; f < 8; ++f) v += bfb[((size_t)l * 8 + f) * 128 + n];
    }
  }
  short s0, s1; split2(v, s0, s1);
  d0[(size_t)l * 40960 + n * 320 + k] = s0;
  d1[(size_t)l * 40960 + n * 320 + k] = s1;
}

// ---------------- prep: angle B matrix [5][n=128][k=64] bf16 x2 --------------
// k layout: k<32 RBF weights Wang[k][n] | 32..36 Wrest | 37 bias (bang+brest) | pad0
__global__ __launch_bounds__(64) void k_prep_ang(
    const float* __restrict__ Wa, const float* __restrict__ ba,
    const float* __restrict__ Wr, const float* __restrict__ br,
    short* __restrict__ d0, short* __restrict__ d1)
{
  int b = blockIdx.x;            // 5*128
  int l = b >> 7, n = b & 127;
  int k = threadIdx.x;           // 0..63
  float v = 0.f;
  if (k < 32)       v = Wa[((size_t)l * 32 + k) * 128 + n];
  else if (k < 37)  v = Wr[((size_t)l * 5 + (k - 32)) * 128 + n];
  else if (k == 37) v = ba[(size_t)l * 128 + n] + br[(size_t)l * 128 + n];
  short s0, s1; split2(v, s0, s1);
  size_t o = (size_t)l * 8192 + n * 64 + k;
  d0[o] = s0; d1[o] = s1;
}

// ---------------- CSR build ----------------
__global__ __launch_bounds__(256) void k_count(
    const int* __restrict__ dst, int* __restrict__ counts, int M)
{
  int i = blockIdx.x * 256 + threadIdx.x;
  if (i < M) atomicAdd(&counts[dst[i]], 1);
}

// phase 1: per-block (1024) exclusive scan -> offs, block total -> bsums
__global__ __launch_bounds__(1024) void k_scan1(
    const int* __restrict__ counts, int* __restrict__ offs,
    int* __restrict__ bsums, int n)
{
  __shared__ int wsum[16];
  int i = blockIdx.x * 1024 + threadIdx.x;
  int lane = threadIdx.x & 63, w = threadIdx.x >> 6;
  int v = (i < n) ? counts[i] : 0;
  int s = v;
#pragma unroll
  for (int d = 1; d < 64; d <<= 1) { int t = __shfl_up(s, d); if (lane >= d) s += t; }
  if (lane == 63) wsum[w] = s;
  __syncthreads();
  int wexcl = 0;
  for (int j = 0; j < w; ++j) wexcl += wsum[j];
  if (i < n) offs[i] = wexcl + (s - v);
  if (threadIdx.x == 1023) bsums[blockIdx.x] = wexcl + s;
}

// phase 2: exclusive scan of block sums (nb <= 256) in one block
__global__ __launch_bounds__(256) void k_scan2(int* __restrict__ bsums, int nb)
{
  __shared__ int wsum[4];
  int lane = threadIdx.x & 63, w = threadIdx.x >> 6;
  int v = ((int)threadIdx.x < nb) ? bsums[threadIdx.x] : 0;
  int s = v;
#pragma unroll
  for (int d = 1; d < 64; d <<= 1) { int t = __shfl_up(s, d); if (lane >= d) s += t; }
  if (lane == 63) wsum[w] = s;
  __syncthreads();
  int wexcl = 0;
  for (int j = 0; j < w; ++j) wexcl += wsum[j];
  if ((int)threadIdx.x < nb) bsums[threadIdx.x] = wexcl + (s - v);
}

// phase 3: add block offset; fused cursor init (replaces D2D memcpy)
__global__ __launch_bounds__(1024) void k_scan3(
    int* __restrict__ offs, const int* __restrict__ bsums,
    int* __restrict__ cursor, int n, int total)
{
  int i = blockIdx.x * 1024 + threadIdx.x;
  if (i < n) {
    int o = offs[i] + bsums[blockIdx.x];
    offs[i] = o;
    cursor[i] = o;
  }
  if (i == 0) offs[n] = total;
}

__global__ __launch_bounds__(256) void k_fill(
    const int* __restrict__ dst, int* __restrict__ cursor,
    int* __restrict__ perm, int M)
{
  int i = blockIdx.x * 256 + threadIdx.x;
  if (i < M) { int p = atomicAdd(&cursor[dst[i]], 1); perm[p] = i; }
}

// sperm[j] = eib_src[perm[j]] (angle source edge, in CSR order) — layer-invariant
__global__ __launch_bounds__(256) void k_sperm(
    const int* __restrict__ perm, const int* __restrict__ eib_src,
    int* __restrict__ sperm, int M)
{
  int i = blockIdx.x * 256 + threadIdx.x;
  if (i < M) sperm[i] = eib_src[perm[i]];
}

// ---------------- atom gather -> pre (fp32) ----------------
template<bool AFF>
__global__ __launch_bounds__(256) void k_atom_gather(
    const int* __restrict__ offs, const int* __restrict__ perm,
    const int* __restrict__ ei,
    const float* __restrict__ h, const float* __restrict__ hB,
    const float* __restrict__ scH, const float* __restrict__ shH,
    const float* __restrict__ scB, const float* __restrict__ shB,
    const float* __restrict__ eps_l, float* __restrict__ pre)
{
  int w = blockIdx.x * 4 + (threadIdx.x >> 6);
  int lane = threadIdx.x & 63;
  int c = lane * 2;
  float2 sH, tH, sB, tB;
  if (AFF) {
    sH = *(const float2*)&scH[c]; tH = *(const float2*)&shH[c];
    sB = *(const float2*)&scB[c]; tB = *(const float2*)&shB[c];
  }
  float ep = 1.f + *eps_l;
  float2 self = *(const float2*)&h[(size_t)w * DD + c];
  if (AFF) {
    self.x = fmaxf(fmaf(self.x, sH.x, tH.x), 0.f);
    self.y = fmaxf(fmaf(self.y, sH.y, tH.y), 0.f);
  }
  float ax = self.x * ep, ay = self.y * ep;
  int jb = offs[w], je = offs[w + 1];
  for (int j = jb; j < je; ++j) {
    int e = perm[j];
    int s = ei[e];
    float2 hv = *(const float2*)&h[(size_t)s * DD + c];
    float2 bv = *(const float2*)&hB[(size_t)e * DD + c];
    if (AFF) {
      hv.x = fmaxf(fmaf(hv.x, sH.x, tH.x), 0.f);
      hv.y = fmaxf(fmaf(hv.y, sH.y, tH.y), 0.f);
      bv.x = fmaxf(fmaf(bv.x, sB.x, tB.x), 0.f);
      bv.y = fmaxf(fmaf(bv.y, sB.y, tB.y), 0.f);
    }
    ax += fmaxf(hv.x + bv.x, 0.f);
    ay += fmaxf(hv.y + bv.y, 0.f);
  }
  *(float2*)&pre[(size_t)w * DD + c] = make_float2(ax, ay);
}

// ---------------- angle gather (streaming) -> pre (fp32) ----------------
// eA: fp16 per-angle embedding in CSR-perm order [AA][128]; sperm: source edge id.
__global__ __launch_bounds__(256) void k_angle_gather2(
    const int* __restrict__ offs, const int* __restrict__ sperm,
    const __half* __restrict__ eA, const float* __restrict__ x,
    const float* __restrict__ eps_l, float* __restrict__ pre)
{
  int w = blockIdx.x * 4 + (threadIdx.x >> 6);
  int lane = threadIdx.x & 63;
  int c = lane * 2;
  float ep = 1.f + *eps_l;
  float2 self = *(const float2*)&x[(size_t)w * DD + c];
  float ax = self.x * ep, ay = self.y * ep;
  int jb = offs[w], je = offs[w + 1];
  for (int j = jb; j < je; ++j) {
    int s = sperm[j];
    __half2 ev = *(const __half2*)&eA[(size_t)j * DD + c];
    float2 ef = __half22float2(ev);
    float2 xs2 = *(const float2*)&x[(size_t)s * DD + c];
    ax += fmaxf(xs2.x + ef.x, 0.f);
    ay += fmaxf(xs2.y + ef.y, 0.f);
  }
  *(float2*)&pre[(size_t)w * DD + c] = make_float2(ax, ay);
}

// ---------------- BN finalize ----------------
__global__ __launch_bounds__(128) void k_bn_finalize(
    const float* __restrict__ sum, const float* __restrict__ sq,
    const float* __restrict__ g, const float* __restrict__ be,
    float* __restrict__ scale, float* __restrict__ shift, float invM)
{
  int c = threadIdx.x;
  float mean = sum[c] * invM;
  float var = sq[c] * invM - mean * mean;
  float s = g[c] / sqrtf(var + 1e-5f);
  scale[c] = s;
  shift[c] = be[c] - mean * s;
}

// ---------------- MFMA bf16x3 GEMM [M,128]@[128,128]+bias ----------------
// Latency-bound fix (R8 post-mortem): A-LDS round trip removed — each wave loads
// its A fragments direct from global (L3-hot, 2x redundancy across wave pairs);
// B double-buffered in LDS (2x20.5KB) -> ONE barrier per K-step guarding only the
// tiny 2-load/thread B stage. Math bit-identical to R8.
template<bool AFF, bool OUT_STATS>
__global__ __launch_bounds__(256, 3) void k_gemm_mfma(
    const float* __restrict__ Af,
    const short* __restrict__ Bt0, const short* __restrict__ Bt1,
    const float* __restrict__ bias, float* __restrict__ out,
    const float* __restrict__ iscale, const float* __restrict__ ishift,
    float* __restrict__ osum, float* __restrict__ osq, int M)
{
  __shared__ short Bs0[2][128][40], Bs1[2][128][40];
  __shared__ float redsum[128], redsq[128];
  int tid = threadIdx.x;
  int row0 = blockIdx.x * 128;
  int lane = tid & 63, wv = tid >> 6;
  int wr = (wv >> 1) * 64, wc = (wv & 1) * 64;
  int l15 = lane & 15, l4 = lane >> 4;

  if (OUT_STATS && tid < 128) { redsum[tid] = 0.f; redsq[tid] = 0.f; }

  f4v acc[4][4];
#pragma unroll
  for (int i = 0; i < 4; ++i)
#pragma unroll
    for (int j = 0; j < 4; ++j) acc[i][j] = (f4v){0.f, 0.f, 0.f, 0.f};

  // stage B for kc=0 into buffer 0
  {
    int n = tid >> 1, o = (tid & 1) * 2;      // 256 threads x 2 chunks of 8
#pragma unroll
    for (int c2 = 0; c2 < 2; ++c2) {
      *(short8v*)&Bs0[0][n][(o + c2) * 8] = *(const short8v*)&Bt0[n * 128 + (o + c2) * 8];
      *(short8v*)&Bs1[0][n][(o + c2) * 8] = *(const short8v*)&Bt1[n * 128 + (o + c2) * 8];
    }
  }
  __syncthreads();

  for (int kc = 0; kc < 4; ++kc) {
    int cur = kc & 1;
    // prefetch next B tile into the other buffer (no barrier until end of iter)
    if (kc < 3) {
      int n = tid >> 1, o = (tid & 1) * 2;
#pragma unroll
      for (int c2 = 0; c2 < 2; ++c2) {
        *(short8v*)&Bs0[cur ^ 1][n][(o + c2) * 8] =
            *(const short8v*)&Bt0[n * 128 + (kc + 1) * 32 + (o + c2) * 8];
        *(short8v*)&Bs1[cur ^ 1][n][(o + c2) * 8] =
            *(const short8v*)&Bt1[n * 128 + (kc + 1) * 32 + (o + c2) * 8];
      }
    }

    // per-kc affine params (same k-range for all mt)
    float4 sca, scb, sha, shb;
    if (AFF) {
      sca = *(const float4*)&iscale[kc * 32 + l4 * 8];
      scb = *(const float4*)&iscale[kc * 32 + l4 * 8 + 4];
      sha = *(const float4*)&ishift[kc * 32 + l4 * 8];
      shb = *(const float4*)&ishift[kc * 32 + l4 * 8 + 4];
    }

    // A fragments direct from global
    short8v fa0[4], fa1[4];
#pragma unroll
    for (int mt = 0; mt < 4; ++mt) {
      int grow = row0 + wr + mt * 16 + l15;
      float4 va = make_float4(0.f, 0.f, 0.f, 0.f);
      float4 vb = make_float4(0.f, 0.f, 0.f, 0.f);
      if (grow < M) {
        const float* p = &Af[(size_t)grow * 128 + kc * 32 + l4 * 8];
        va = *(const float4*)p;
        vb = *(const float4*)(p + 4);
        if (AFF) {
          va.x = fmaxf(fmaf(va.x, sca.x, sha.x), 0.f);
          va.y = fmaxf(fmaf(va.y, sca.y, sha.y), 0.f);
          va.z = fmaxf(fmaf(va.z, sca.z, sha.z), 0.f);
          va.w = fmaxf(fmaf(va.w, sca.w, sha.w), 0.f);
          vb.x = fmaxf(fmaf(vb.x, scb.x, shb.x), 0.f);
          vb.y = fmaxf(fmaf(vb.y, scb.y, shb.y), 0.f);
          vb.z = fmaxf(fmaf(vb.z, scb.z, shb.z), 0.f);
          vb.w = fmaxf(fmaf(vb.w, scb.w, shb.w), 0.f);
        }
      }
      short a0[8], a1[8];
      split2(va.x, a0[0], a1[0]);
      split2(va.y, a0[1], a1[1]);
      split2(va.z, a0[2], a1[2]);
      split2(va.w, a0[3], a1[3]);
      split2(vb.x, a0[4], a1[4]);
      split2(vb.y, a0[5], a1[5]);
      split2(vb.z, a0[6], a1[6]);
      split2(vb.w, a0[7], a1[7]);
      fa0[mt] = (short8v){a0[0], a0[1], a0[2], a0[3], a0[4], a0[5], a0[6], a0[7]};
      fa1[mt] = (short8v){a1[0], a1[1], a1[2], a1[3], a1[4], a1[5], a1[6], a1[7]};
    }

    short8v fb0[4], fb1[4];
#pragma unroll
    for (int nt = 0; nt < 4; ++nt) fb0[nt] = *(const short8v*)&Bs0[cur][wc + nt * 16 + l15][l4 * 8];
#pragma unroll
    for (int mt = 0; mt < 4; ++mt)
#pragma unroll
      for (int nt = 0; nt < 4; ++nt)
        acc[mt][nt] = __builtin_amdgcn_mfma_f32_16x16x32_bf16(fa0[mt], fb0[nt], acc[mt][nt], 0, 0, 0);
#pragma unroll
    for (int nt = 0; nt < 4; ++nt) fb1[nt] = *(const short8v*)&Bs1[cur][wc + nt * 16 + l15][l4 * 8];
#pragma unroll
    for (int mt = 0; mt < 4; ++mt)
#pragma unroll
      for (int nt = 0; nt < 4; ++nt)
        acc[mt][nt] = __builtin_amdgcn_mfma_f32_16x16x32_bf16(fa0[mt], fb1[nt], acc[mt][nt], 0, 0, 0);
#pragma unroll
    for (int mt = 0; mt < 4; ++mt)
#pragma unroll
      for (int nt = 0; nt < 4; ++nt)
        acc[mt][nt] = __builtin_amdgcn_mfma_f32_16x16x32_bf16(fa1[mt], fb0[nt], acc[mt][nt], 0, 0, 0);
    __syncthreads();   // B[cur] reads done; B[cur^1] writes visible for next iter
  }

  // epilogue
  float cs[4], cq[4];
#pragma unroll
  for (int nt = 0; nt < 4; ++nt) { cs[nt] = 0.f; cq[nt] = 0.f; }
#pragma unroll
  for (int nt = 0; nt < 4; ++nt) {
    int col = wc + nt * 16 + l15;
    float bv = bias[col];
#pragma unroll
    for (int mt = 0; mt < 4; ++mt) {
#pragma unroll
      for (int j = 0; j < 4; ++j) {
        int gr = row0 + wr + mt * 16 + l4 * 4 + j;
        if (gr < M) {
          float o = acc[mt][nt][j] + bv;
          out[(size_t)gr * 128 + col] = o;
          if (OUT_STATS) { cs[nt] += o; cq[nt] += o * o; }
        }
      }
    }
  }
  if (OUT_STATS) {
#pragma unroll
    for (int nt = 0; nt < 4; ++nt) {
      int col = wc + nt * 16 + l15;
      atomicAdd(&redsum[col], cs[nt]);
      atomicAdd(&redsq[col],  cq[nt]);
    }
    __syncthreads();
    if (tid < 128) {
      atomicAdd(&osum[tid], redsum[tid]);
      atomicAdd(&osq[tid],  redsq[tid]);
    }
  }
}

// ---------------- bond embed as MFMA bf16x3 GEMM [E,320]@[320,128] ----------------
// x3 scheme: A0B0 + A0B1 + A1B0 (one-hot chunks: A exact -> A0B0 + A0B1).
__global__ __launch_bounds__(256) void k_bond_mfma(
    const float* __restrict__ xf, const int* __restrict__ eai,
    const short* __restrict__ Bt0, const short* __restrict__ Bt1,
    float* __restrict__ out)
{
  __shared__ short As0[128][40], As1[128][40];
  __shared__ short Bs0[128][40], Bs1[128][40];
  __shared__ float xfs[128][8];
  __shared__ int   iis[128][3];
  int tid = threadIdx.x;
  int e0 = blockIdx.x * 128;
  int lane = tid & 63, wv = tid >> 6;
  int wr = (wv >> 1) * 64, wc = (wv & 1) * 64;
  int l15 = lane & 15, l4 = lane >> 4;

  // stage xf: 128 edges x 8 floats = 256 float4 chunks -> exactly one pass.
  {
    int e = tid >> 1, f4i = (tid & 1) * 4;
    float4 v = make_float4(1e15f, 1e15f, 1e15f, 1e15f);
    if (e0 + e < EE) v = *(const float4*)&xf[(size_t)(e0 + e) * 8 + f4i];
    xfs[e][f4i] = v.x; xfs[e][f4i + 1] = v.y; xfs[e][f4i + 2] = v.z; xfs[e][f4i + 3] = v.w;
  }
  if (tid < 128) {
    int e = tid;
    if (e0 + e < EE) {
      iis[e][0] = eai[(size_t)(e0 + e) * 3];
      iis[e][1] = eai[(size_t)(e0 + e) * 3 + 1];
      iis[e][2] = eai[(size_t)(e0 + e) * 3 + 2];
    } else { iis[e][0] = -1; iis[e][1] = -1; iis[e][2] = -1; }
  }
  __syncthreads();

  f4v acc[4][4];
#pragma unroll
  for (int i = 0; i < 4; ++i)
#pragma unroll
    for (int j = 0; j < 4; ++j) acc[i][j] = (f4v){0.f, 0.f, 0.f, 0.f};

  for (int kc = 0; kc < 10; ++kc) {
#pragma unroll
    for (int i = 0; i < 2; ++i) {
      int vid = tid + i * 256;
      int n = vid >> 2, o = vid & 3;
      *(short8v*)&Bs0[n][o * 8] = *(const short8v*)&Bt0[n * 320 + kc * 32 + o * 8];
      *(short8v*)&Bs1[n][o * 8] = *(const short8v*)&Bt1[n * 320 + kc * 32 + o * 8];
    }
    // build A chunk
#pragma unroll
    for (int i = 0; i < 2; ++i) {
      int vid = tid + i * 256;
      int e = vid >> 2, o = vid & 3;
      int ts = o * 8;
      if (kc < 8) {
        float x = xfs[e][kc];
        float gam = c_bf_gam[kc], st = c_bf_start[kc], sp = c_bf_step[kc];
        int cnt = c_bf_cnt[kc];
        short a0[8], a1[8];
#pragma unroll
        for (int j = 0; j < 8; ++j) {
          int t = ts + j;
          float dx = x - (st + sp * (float)t);
          float v = (t < cnt) ? __expf(-gam * dx * dx) : 0.f;
          split2(v, a0[j], a1[j]);
        }
        short8v v0 = {a0[0], a0[1], a0[2], a0[3], a0[4], a0[5], a0[6], a0[7]};
        short8v v1 = {a1[0], a1[1], a1[2], a1[3], a1[4], a1[5], a1[6], a1[7]};
        *(short8v*)&As0[e][ts] = v0;
        *(short8v*)&As1[e][ts] = v1;
      } else {
        short a0[8];
        if (kc == 8) {
          int i0 = iis[e][0], i1 = iis[e][1];
#pragma unroll
          for (int j = 0; j < 8; ++j) {
            int t = ts + j;
            float v = (t < 12) ? (t == i0 ? 1.f : 0.f)
                    : (t < 24) ? ((t - 12) == i1 ? 1.f : 0.f) : 0.f;
            a0[j] = f2bf(v);
          }
        } else {
          int i2 = iis[e][2];
#pragma unroll
          for (int j = 0; j < 8; ++j) {
            int t = ts + j;
            float v = (t < 12) ? (t == i2 ? 1.f : 0.f) : (t == 12 ? 1.f : 0.f);
            a0[j] = f2bf(v);
          }
        }
        short8v v0 = {a0[0], a0[1], a0[2], a0[3], a0[4], a0[5], a0[6], a0[7]};
        *(short8v*)&As0[e][ts] = v0;
      }
    }
    __syncthreads();

    short8v fa0[4], fa1[4], fb0[4], fb1[4];
#pragma unroll
    for (int mt = 0; mt < 4; ++mt) fa0[mt] = *(const short8v*)&As0[wr + mt * 16 + l15][l4 * 8];
#pragma unroll
    for (int nt = 0; nt < 4; ++nt) fb0[nt] = *(const short8v*)&Bs0[wc + nt * 16 + l15][l4 * 8];
#pragma unroll
    for (int mt = 0; mt < 4; ++mt)
#pragma unroll
      for (int nt = 0; nt < 4; ++nt)
        acc[mt][nt] = __builtin_amdgcn_mfma_f32_16x16x32_bf16(fa0[mt], fb0[nt], acc[mt][nt], 0, 0, 0);
#pragma unroll
    for (int nt = 0; nt < 4; ++nt) fb1[nt] = *(const short8v*)&Bs1[wc + nt * 16 + l15][l4 * 8];
#pragma unroll
    for (int mt = 0; mt < 4; ++mt)
#pragma unroll
      for (int nt = 0; nt < 4; ++nt)
        acc[mt][nt] = __builtin_amdgcn_mfma_f32_16x16x32_bf16(fa0[mt], fb1[nt], acc[mt][nt], 0, 0, 0);
    if (kc < 8) {
#pragma unroll
      for (int mt = 0; mt < 4; ++mt) fa1[mt] = *(const short8v*)&As1[wr + mt * 16 + l15][l4 * 8];
#pragma unroll
      for (int mt = 0; mt < 4; ++mt)
#pragma unroll
        for (int nt = 0; nt < 4; ++nt)
          acc[mt][nt] = __builtin_amdgcn_mfma_f32_16x16x32_bf16(fa1[mt], fb0[nt], acc[mt][nt], 0, 0, 0);
    }
    __syncthreads();
  }

#pragma unroll
  for (int nt = 0; nt < 4; ++nt) {
    int col = wc + nt * 16 + l15;
#pragma unroll
    for (int mt = 0; mt < 4; ++mt) {
#pragma unroll
      for (int j = 0; j < 4; ++j) {
        int ge = e0 + wr + mt * 16 + l4 * 4 + j;
        if (ge < EE) out[(size_t)ge * 128 + col] = acc[mt][nt][j];
      }
    }
  }
}

// ---------------- angle embed as MFMA bf16x3 GEMM [A,64]@[64,128], perm order ----
// Row j computes the embedding of angle a=perm[j]; output fp16 [AA][128].
__global__ __launch_bounds__(256) void k_ang_mfma(
    const int* __restrict__ perm, const float* __restrict__ xba,
    const short* __restrict__ Bt0, const short* __restrict__ Bt1,
    __half* __restrict__ out)
{
  __shared__ short As0[128][40], As1[128][40];
  __shared__ short Bs0[128][40], Bs1[128][40];
  __shared__ float xs[128][6];
  int tid = threadIdx.x;
  int j0 = blockIdx.x * 128;      // AA % 128 == 0, no guards needed
  int lane = tid & 63, wv = tid >> 6;
  int wr = (wv >> 1) * 64, wc = (wv & 1) * 64;
  int l15 = lane & 15, l4 = lane >> 4;

  if (tid < 128) {
    int a = perm[j0 + tid];
    const float* p = &xba[(size_t)a * 6];
#pragma unroll
    for (int q = 0; q < 6; ++q) xs[tid][q] = p[q];
  }
  __syncthreads();

  f4v acc[4][4];
#pragma unroll
  for (int i = 0; i < 4; ++i)
#pragma unroll
    for (int j = 0; j < 4; ++j) acc[i][j] = (f4v){0.f, 0.f, 0.f, 0.f};

  for (int kc = 0; kc < 2; ++kc) {
#pragma unroll
    for (int i = 0; i < 2; ++i) {
      int vid = tid + i * 256;
      int n = vid >> 2, o = vid & 3;
      *(short8v*)&Bs0[n][o * 8] = *(const short8v*)&Bt0[n * 64 + kc * 32 + o * 8];
      *(short8v*)&Bs1[n][o * 8] = *(const short8v*)&Bt1[n * 64 + kc * 32 + o * 8];
    }
#pragma unroll
    for (int i = 0; i < 2; ++i) {
      int vid = tid + i * 256;
      int r = vid >> 2, o = vid & 3;
      int ts = o * 8;
      short a0[8], a1[8];
      if (kc == 0) {
        float x0 = xs[r][0];
#pragma unroll
        for (int j = 0; j < 8; ++j) {
          float d = x0 - 0.1f * (float)(ts + j);
          split2(__expf(-10.f * d * d), a0[j], a1[j]);
        }
      } else {
#pragma unroll
        for (int j = 0; j < 8; ++j) {
          int t = ts + j;
          float v = (t < 5) ? xs[r][1 + t] : (t == 5 ? 1.f : 0.f);
          split2(v, a0[j], a1[j]);
        }
      }
      short8v v0 = {a0[0], a0[1], a0[2], a0[3], a0[4], a0[5], a0[6], a0[7]};
      short8v v1 = {a1[0], a1[1], a1[2], a1[3], a1[4], a1[5], a1[6], a1[7]};
      *(short8v*)&As0[r][ts] = v0;
      *(short8v*)&As1[r][ts] = v1;
    }
    __syncthreads();

    short8v fa0[4], fa1[4], fb0[4], fb1[4];
#pragma unroll
    for (int mt = 0; mt < 4; ++mt) fa0[mt] = *(const short8v*)&As0[wr + mt * 16 + l15][l4 * 8];
#pragma unroll
    for (int nt = 0; nt < 4; ++nt) fb0[nt] = *(const short8v*)&Bs0[wc + nt * 16 + l15][l4 * 8];
#pragma unroll
    for (int mt = 0; mt < 4; ++mt)
#pragma unroll
      for (int nt = 0; nt < 4; ++nt)
        acc[mt][nt] = __builtin_amdgcn_mfma_f32_16x16x32_bf16(fa0[mt], fb0[nt], acc[mt][nt], 0, 0, 0);
#pragma unroll
    for (int nt = 0; nt < 4; ++nt) fb1[nt] = *(const short8v*)&Bs1[wc + nt * 16 + l15][l4 * 8];
#pragma unroll
    for (int mt = 0; mt < 4; ++mt)
#pragma unroll
      for (int nt = 0; nt < 4; ++nt)
        acc[mt][nt] = __builtin_amdgcn_mfma_f32_16x16x32_bf16(fa0[mt], fb1[nt], acc[mt][nt], 0, 0, 0);
#pragma unroll
    for (int mt = 0; mt < 4; ++mt) fa1[mt] = *(const short8v*)&As1[wr + mt * 16 + l15][l4 * 8];
#pragma unroll
    for (int mt = 0; mt < 4; ++mt)
#pragma unroll
      for (int nt = 0; nt < 4; ++nt)
        acc[mt][nt] = __builtin_amdgcn_mfma_f32_16x16x32_bf16(fa1[mt], fb0[nt], acc[mt][nt], 0, 0, 0);
    __syncthreads();
  }

#pragma unroll
  for (int nt = 0; nt < 4; ++nt) {
    int col = wc + nt * 16 + l15;
#pragma unroll
    for (int mt = 0; mt < 4; ++mt) {
#pragma unroll
      for (int j = 0; j < 4; ++j) {
        int gj = j0 + wr + mt * 16 + l4 * 4 + j;
        out[(size_t)gj * DD + col] = __float2half(acc[mt][nt][j]);
      }
    }
  }
}

extern "C" void kernel_launch(void* const* d_in, const int* in_sizes, int n_in,
                              void* d_out, int out_size, void* d_ws, size_t ws_size,
                              hipStream_t stream)
{
  (void)in_sizes; (void)n_in; (void)out_size; (void)ws_size;
  const int*   x_atom = (const int*)  d_in[0];
  const int*   ei     = (const int*)  d_in[1];
  const int*   eai    = (const int*)  d_in[2];
  const int*   eib    = (const int*)  d_in[3];
  const float* xf     = (const float*)d_in[4];
  const float* xba    = (const float*)d_in[5];
  const float* atab   = (const float*)d_in[6];
  const float* btab   = (const float*)d_in[7];
  const float* bfW    = (const float*)d_in[8];
  const float* bfb    = (const float*)d_in[9];
  const float* Wang   = (const float*)d_in[10];
  const float* bang   = (const float*)d_in[11];
  const float* Wrest  = (const float*)d_in[12];
  const float* brest  = (const float*)d_in[13];
  const float* eps_a  = (const float*)d_in[14];
  const float* W1_a   = (const float*)d_in[15];
  const float* b1_a   = (const float*)d_in[16];
  const float* bng_a  = (const float*)d_in[17];
  const float* bnb_a  = (const float*)d_in[18];
  const float* W2_a   = (const float*)d_in[19];
  const float* b2_a   = (const float*)d_in[20];
  const float* eps_g  = (const float*)d_in[21];
  const float* W1_g   = (const float*)d_in[22];
  const float* b1_g   = (const float*)d_in[23];
  const float* bng_g  = (const float*)d_in[24];
  const float* bnb_g  = (const float*)d_in[25];
  const float* W2_g   = (const float*)d_in[26];
  const float* b2_g   = (const float*)d_in[27];
  const float* obng_a = (const float*)d_in[28];
  const float* obnb_a = (const float*)d_in[29];
  const float* obng_b = (const float*)d_in[30];
  const float* obnb_b = (const float*)d_in[31];

  float* out_a = (float*)d_out;
  float* out_b = out_a + (size_t)NN * DD;
  char* base = (char*)d_ws;
  const size_t ED = (size_t)EE * DD, ND = (size_t)NN * DD;

  float* preB  = (float*)base;                 base += ED * 4;          // 102.4 MB
  float* T     = (float*)base;                 base += ED * 4;          // 102.4 MB
  float* hB0   = (float*)base;                 base += ED * 4;          // 102.4 MB
  float* hA0   = (float*)base;                 base += ND * 4;          // 51.2 MB
  float* stats = (float*)base;                 base += 1280 * 4;
  float* sum1 = stats,        *sq1 = stats + 128;
  float* sum2 = stats + 256,  *sq2 = stats + 384;
  float* sc1  = stats + 512,  *sh1 = stats + 640;
  float* oscH = stats + 768,  *oshH = stats + 896;
  float* oscB = stats + 1024, *oshB = stats + 1152;
  int* offsA = (int*)base;                     base += (NN + 1) * 4;
  int* permA = (int*)base;                     base += (size_t)EE * 4;
  int* offsB = (int*)base;                     base += (EE + 1) * 4;
  int* permB = (int*)base;                     base += (size_t)AA * 4;
  int* curA  = (int*)base;                     base += (size_t)NN * 4;
  int* curB  = (int*)base;                     base += (size_t)EE * 4;
  short* Wt0 = (short*)base;                   base += 20 * 16384 * 2;  // [4 grp][5][n][k]
  short* Wt1 = (short*)base;                   base += 20 * 16384 * 2;
  short* Bt0 = (short*)base;                   base += 6 * 40960 * 2;   // [6][n][320]
  short* Bt1 = (short*)base;                   base += 6 * 40960 * 2;
  base = (char*)(((uintptr_t)base + 15) & ~(uintptr_t)15);
  short* Ang0 = (short*)base;                  base += 5 * 8192 * 2;    // [5][n=128][k=64]
  short* Ang1 = (short*)base;                  base += 5 * 8192 * 2;
  int* spermB = (int*)base;                    base += (size_t)AA * 4;  // 1.6 MB
  int* bsumA  = (int*)base;                    base += 256 * 4;
  int* bsumB  = (int*)base;                    base += 256 * 4;

  // ---- prep: weight transpose/split ----
  k_prep_w<<<5 * 128, 128, 0, stream>>>(W1_a, Wt0,              Wt1);
  k_prep_w<<<5 * 128, 128, 0, stream>>>(W2_a, Wt0 + 5 * 16384,  Wt1 + 5 * 16384);
  k_prep_w<<<5 * 128, 128, 0, stream>>>(W1_g, Wt0 + 10 * 16384, Wt1 + 10 * 16384);
  k_prep_w<<<5 * 128, 128, 0, stream>>>(W2_g, Wt0 + 15 * 16384, Wt1 + 15 * 16384);
  k_prep_bond<<<6 * 128, 320, 0, stream>>>(bfW, btab, bfb, Bt0, Bt1);
  k_prep_ang<<<5 * 128, 64, 0, stream>>>(Wang, bang, Wrest, brest, Ang0, Ang1);

  // ---- CSR build (parallel 3-phase scan) ----
  hipMemsetAsync(curA, 0, NN * sizeof(int), stream);
  hipMemsetAsync(curB, 0, EE * sizeof(int), stream);
  k_count<<<(EE + 255) / 256, 256, 0, stream>>>(ei + EE, curA, EE);
  k_count<<<(AA + 255) / 256, 256, 0, stream>>>(eib + AA, curB, AA);
  const int nbA = (NN + 1023) / 1024, nbB = (EE + 1023) / 1024;
  k_scan1<<<nbA, 1024, 0, stream>>>(curA, offsA, bsumA, NN);
  k_scan1<<<nbB, 1024, 0, stream>>>(curB, offsB, bsumB, EE);
  k_scan2<<<1, 256, 0, stream>>>(bsumA, nbA);
  k_scan2<<<1, 256, 0, stream>>>(bsumB, nbB);
  k_scan3<<<nbA, 1024, 0, stream>>>(offsA, bsumA, curA, NN, EE);
  k_scan3<<<nbB, 1024, 0, stream>>>(offsB, bsumB, curB, EE, AA);
  k_fill<<<(EE + 255) / 256, 256, 0, stream>>>(ei + EE, curA, permA, EE);
  k_fill<<<(AA + 255) / 256, 256, 0, stream>>>(eib + AA, curB, permB, AA);
  k_sperm<<<(AA + 255) / 256, 256, 0, stream>>>(permB, eib, spermB, AA);

  // ---- initial embeddings ----
  k_atom_embed<<<NN, 128, 0, stream>>>(x_atom, atab, hA0);
  const int gB = (EE + 127) / 128;
  k_bond_mfma<<<gB, 256, 0, stream>>>(xf, eai, Bt0, Bt1, hB0);

  const int gA = (NN + 127) / 128;
  float* hA_cur = hA0;
  float* hB_cur = hB0;
  for (int l = 0; l < LL; ++l) {
    float* hA_nxt = (l & 1) ? hA0 : out_a;
    float* hB_nxt = (l & 1) ? hB0 : out_b;
    const bool obn = (l < LL - 1);
    size_t o1a = (size_t)l * 16384, o2a = (size_t)(5 + l) * 16384;
    size_t o1g = (size_t)(10 + l) * 16384, o2g = (size_t)(15 + l) * 16384;

    // ---- atom GIN conv ----
    if (l == 0)
      k_atom_gather<false><<<NN / 4, 256, 0, stream>>>(
          offsA, permA, ei, hA_cur, hB_cur, nullptr, nullptr, nullptr, nullptr,
          eps_a + l, preB);
    else
      k_atom_gather<true><<<NN / 4, 256, 0, stream>>>(
          offsA, permA, ei, hA_cur, hB_cur, oscH, oshH, oscB, oshB,
          eps_a + l, preB);
    // hB_cur is dead after atom_gather: reuse its 102.4 MB as the fp16 angle
    // embedding buffer (AA*128*2B == EE*128*4B). Stream order guarantees the
    // gather has consumed it before k_ang_mfma overwrites.
    __half* eAh = (__half*)hB_cur;
    k_ang_mfma<<<AA / 128, 256, 0, stream>>>(
        permB, xba, Ang0 + (size_t)l * 8192, Ang1 + (size_t)l * 8192, eAh);
    hipMemsetAsync(stats, 0, 512 * sizeof(float), stream);
    k_gemm_mfma<false, true><<<gA, 256, 0, stream>>>(
        preB, Wt0 + o1a, Wt1 + o1a,
        b1_a + l * DD, T, nullptr, nullptr, sum1, sq1, NN);
    k_bn_finalize<<<1, 128, 0, stream>>>(sum1, sq1, bng_a + l * DD, bnb_a + l * DD, sc1, sh1, 1.f / NN);
    if (obn) {
      k_gemm_mfma<true, true><<<gA, 256, 0, stream>>>(
          T, Wt0 + o2a, Wt1 + o2a,
          b2_a + l * DD, hA_nxt, sc1, sh1, sum2, sq2, NN);
      k_bn_finalize<<<1, 128, 0, stream>>>(sum2, sq2, obng_a + l * DD, obnb_a + l * DD, oscH, oshH, 1.f / NN);
    } else {
      k_gemm_mfma<true, false><<<gA, 256, 0, stream>>>(
          T, Wt0 + o2a, Wt1 + o2a,
          b2_a + l * DD, hA_nxt, sc1, sh1, nullptr, nullptr, NN);
    }

    // ---- bond GIN conv ----
    k_bond_mfma<<<gB, 256, 0, stream>>>(
        xf, eai, Bt0 + (size_t)(l + 1) * 40960, Bt1 + (size_t)(l + 1) * 40960, T);
    k_angle_gather2<<<EE / 4, 256, 0, stream>>>(
        offsB, spermB, eAh, T, eps_g + l, preB);
    hipMemsetAsync(stats, 0, 512 * sizeof(float), stream);
    k_gemm_mfma<false, true><<<gB, 256, 0, stream>>>(
        preB, Wt0 + o1g, Wt1 + o1g,
        b1_g + l * DD, T, nullptr, nullptr, sum1, sq1, EE);
    k_bn_finalize<<<1, 128, 0, stream>>>(sum1, sq1, bng_g + l * DD, bnb_g + l * DD, sc1, sh1, 1.f / EE);
    if (obn) {
      k_gemm_mfma<true, true><<<gB, 256, 0, stream>>>(
          T, Wt0 + o2g, Wt1 + o2g,
          b2_g + l * DD, hB_nxt, sc1, sh1, sum2, sq2, EE);
      k_bn_finalize<<<1, 128, 0, stream>>>(sum2, sq2, obng_b + l * DD, obnb_b + l * DD, oscB, oshB, 1.f / EE);
    } else {
      k_gemm_mfma<true, false><<<gB, 256, 0, stream>>>(
          T, Wt0 + o2g, Wt1 + o2g,
          b2_g + l * DD, hB_nxt, sc1, sh1, nullptr, nullptr, EE);
    }

    hA_cur = hA_nxt;
    hB_cur = hB_nxt;
  }
}

// Round 10
// 3798.647 us; speedup vs baseline: 1.1137x; 1.1137x over previous
//
#include <hip/hip_runtime.h>
#include <hip/hip_fp16.h>
#include <cstdint>
#include <cstddef>

#define NN 100000
#define EE 200000
#define AA 400000
#define DD 128
#define LL 5

typedef __attribute__((ext_vector_type(8))) short short8v;   // 8 bf16 (4 VGPRs)
typedef __attribute__((ext_vector_type(4))) float f4v;       // MFMA acc

__constant__ float c_bf_start[8] = {0.f, 0.f, 3.f, 0.f, 0.f, 0.f, 0.f, 0.f};
__constant__ float c_bf_step[8]  = {0.1f, 0.05f, 0.3f, 0.05f, 0.05f, 0.05f, 0.5f, 0.05f};
__constant__ int   c_bf_cnt[8]   = {20, 20, 30, 20, 20, 20, 20, 20};
__constant__ float c_bf_gam[8]   = {10.f, 1.f, 1.f, 1.f, 1.f, 1.f, 2.f, 1.f};

__device__ inline short f2bf(float v) {
  unsigned u = __float_as_uint(v);
  unsigned r = (u + 0x7fffu + ((u >> 16) & 1u)) >> 16;   // RNE
  return (short)r;
}
__device__ inline float bf2f(short h) { return __uint_as_float(((unsigned)(unsigned short)h) << 16); }
// 2-way split: v = s0 + s1 + O(2^-17 |v|)
__device__ inline void split2(float v, short& s0, short& s1) {
  s0 = f2bf(v);
  float r1 = v - bf2f(s0);
  s1 = f2bf(r1);
}

// ---------------- atom embedding ----------------
__global__ __launch_bounds__(128) void k_atom_embed(
    const int* __restrict__ xa, const float* __restrict__ tab, float* __restrict__ h)
{
  __shared__ int idx[9];
  int n = blockIdx.x, d = threadIdx.x;
  if (d < 9) idx[d] = xa[n * 9 + d];
  __syncthreads();
  float s = 0.f;
#pragma unroll
  for (int f = 0; f < 9; ++f) s += tab[(f * 124 + idx[f]) * DD + d];
  h[(size_t)n * DD + d] = s;
}

// ---------------- prep: W[k][n] -> Wt planes [n][k] bf16 x2 (5 mats per call) ----
__global__ __launch_bounds__(128) void k_prep_w(
    const float* __restrict__ src,
    short* __restrict__ d0, short* __restrict__ d1)
{
  int b = blockIdx.x;            // 5*128
  int l = b >> 7, n = b & 127;
  int k = threadIdx.x;
  float v = src[l * 16384 + k * 128 + n];
  short s0, s1; split2(v, s0, s1);
  d0[l * 16384 + n * 128 + k] = s0;
  d1[l * 16384 + n * 128 + k] = s1;
}

// ---------------- prep: bond B matrix [6][n=128][k=320] bf16 x2 --------------
__global__ __launch_bounds__(320) void k_prep_bond(
    const float* __restrict__ bfW,    // [6][8][30][128]
    const float* __restrict__ btab,   // [6][3][12][128]
    const float* __restrict__ bfb,    // [6][8][128]
    short* __restrict__ d0, short* __restrict__ d1)
{
  int b = blockIdx.x;            // 6*128
  int l = b >> 7, n = b & 127;
  int k = threadIdx.x;           // 0..319
  float v = 0.f;
  if (k < 256) {
    int f = k >> 5, c = k & 31;
    if (c < 30) v = bfW[(((size_t)l * 8 + f) * 30 + c) * 128 + n];
  } else if (k < 288) {
    int j = k - 256;
    if (j < 12)       v = btab[(((size_t)l * 3 + 0) * 12 + j) * 128 + n];
    else if (j < 24)  v = btab[(((size_t)l * 3 + 1) * 12 + (j - 12)) * 128 + n];
  } else {
    int j = k - 288;
    if (j < 12)       v = btab[(((size_t)l * 3 + 2) * 12 + j) * 128 + n];
    else if (j == 12) {
      for (int f = 0; f < 8; ++f) v += bfb[((size_t)l * 8 + f) * 128 + n];
    }
  }
  short s0, s1; split2(v, s0, s1);
  d0[(size_t)l * 40960 + n * 320 + k] = s0;
  d1[(size_t)l * 40960 + n * 320 + k] = s1;
}

// ---------------- prep: angle B matrix [5][n=128][k=64] bf16 x2 --------------
__global__ __launch_bounds__(64) void k_prep_ang(
    const float* __restrict__ Wa, const float* __restrict__ ba,
    const float* __restrict__ Wr, const float* __restrict__ br,
    short* __restrict__ d0, short* __restrict__ d1)
{
  int b = blockIdx.x;            // 5*128
  int l = b >> 7, n = b & 127;
  int k = threadIdx.x;           // 0..63
  float v = 0.f;
  if (k < 32)       v = Wa[((size_t)l * 32 + k) * 128 + n];
  else if (k < 37)  v = Wr[((size_t)l * 5 + (k - 32)) * 128 + n];
  else if (k == 37) v = ba[(size_t)l * 128 + n] + br[(size_t)l * 128 + n];
  short s0, s1; split2(v, s0, s1);
  size_t o = (size_t)l * 8192 + n * 64 + k;
  d0[o] = s0; d1[o] = s1;
}

// ---------------- CSR build ----------------
__global__ __launch_bounds__(256) void k_count(
    const int* __restrict__ dst, int* __restrict__ counts, int M)
{
  int i = blockIdx.x * 256 + threadIdx.x;
  if (i < M) atomicAdd(&counts[dst[i]], 1);
}

__global__ __launch_bounds__(1024) void k_scan1(
    const int* __restrict__ counts, int* __restrict__ offs,
    int* __restrict__ bsums, int n)
{
  __shared__ int wsum[16];
  int i = blockIdx.x * 1024 + threadIdx.x;
  int lane = threadIdx.x & 63, w = threadIdx.x >> 6;
  int v = (i < n) ? counts[i] : 0;
  int s = v;
#pragma unroll
  for (int d = 1; d < 64; d <<= 1) { int t = __shfl_up(s, d); if (lane >= d) s += t; }
  if (lane == 63) wsum[w] = s;
  __syncthreads();
  int wexcl = 0;
  for (int j = 0; j < w; ++j) wexcl += wsum[j];
  if (i < n) offs[i] = wexcl + (s - v);
  if (threadIdx.x == 1023) bsums[blockIdx.x] = wexcl + s;
}

__global__ __launch_bounds__(256) void k_scan2(int* __restrict__ bsums, int nb)
{
  __shared__ int wsum[4];
  int lane = threadIdx.x & 63, w = threadIdx.x >> 6;
  int v = ((int)threadIdx.x < nb) ? bsums[threadIdx.x] : 0;
  int s = v;
#pragma unroll
  for (int d = 1; d < 64; d <<= 1) { int t = __shfl_up(s, d); if (lane >= d) s += t; }
  if (lane == 63) wsum[w] = s;
  __syncthreads();
  int wexcl = 0;
  for (int j = 0; j < w; ++j) wexcl += wsum[j];
  if ((int)threadIdx.x < nb) bsums[threadIdx.x] = wexcl + (s - v);
}

__global__ __launch_bounds__(1024) void k_scan3(
    int* __restrict__ offs, const int* __restrict__ bsums,
    int* __restrict__ cursor, int n, int total)
{
  int i = blockIdx.x * 1024 + threadIdx.x;
  if (i < n) {
    int o = offs[i] + bsums[blockIdx.x];
    offs[i] = o;
    cursor[i] = o;
  }
  if (i == 0) offs[n] = total;
}

__global__ __launch_bounds__(256) void k_fill(
    const int* __restrict__ dst, int* __restrict__ cursor,
    int* __restrict__ perm, int M)
{
  int i = blockIdx.x * 256 + threadIdx.x;
  if (i < M) { int p = atomicAdd(&cursor[dst[i]], 1); perm[p] = i; }
}

// sperm[j] = eib_src[perm[j]] (angle source edge, in CSR order) — layer-invariant
__global__ __launch_bounds__(256) void k_sperm(
    const int* __restrict__ perm, const int* __restrict__ eib_src,
    int* __restrict__ sperm, int M)
{
  int i = blockIdx.x * 256 + threadIdx.x;
  if (i < M) sperm[i] = eib_src[perm[i]];
}

// ---------------- atom gather -> pre (fp32) ----------------
template<bool AFF>
__global__ __launch_bounds__(256) void k_atom_gather(
    const int* __restrict__ offs, const int* __restrict__ perm,
    const int* __restrict__ ei,
    const float* __restrict__ h, const float* __restrict__ hB,
    const float* __restrict__ scH, const float* __restrict__ shH,
    const float* __restrict__ scB, const float* __restrict__ shB,
    const float* __restrict__ eps_l, float* __restrict__ pre)
{
  int w = blockIdx.x * 4 + (threadIdx.x >> 6);
  int lane = threadIdx.x & 63;
  int c = lane * 2;
  float2 sH, tH, sB, tB;
  if (AFF) {
    sH = *(const float2*)&scH[c]; tH = *(const float2*)&shH[c];
    sB = *(const float2*)&scB[c]; tB = *(const float2*)&shB[c];
  }
  float ep = 1.f + *eps_l;
  float2 self = *(const float2*)&h[(size_t)w * DD + c];
  if (AFF) {
    self.x = fmaxf(fmaf(self.x, sH.x, tH.x), 0.f);
    self.y = fmaxf(fmaf(self.y, sH.y, tH.y), 0.f);
  }
  float ax = self.x * ep, ay = self.y * ep;
  int jb = offs[w], je = offs[w + 1];
  for (int j = jb; j < je; ++j) {
    int e = perm[j];
    int s = ei[e];
    float2 hv = *(const float2*)&h[(size_t)s * DD + c];
    float2 bv = *(const float2*)&hB[(size_t)e * DD + c];
    if (AFF) {
      hv.x = fmaxf(fmaf(hv.x, sH.x, tH.x), 0.f);
      hv.y = fmaxf(fmaf(hv.y, sH.y, tH.y), 0.f);
      bv.x = fmaxf(fmaf(bv.x, sB.x, tB.x), 0.f);
      bv.y = fmaxf(fmaf(bv.y, sB.y, tB.y), 0.f);
    }
    ax += fmaxf(hv.x + bv.x, 0.f);
    ay += fmaxf(hv.y + bv.y, 0.f);
  }
  *(float2*)&pre[(size_t)w * DD + c] = make_float2(ax, ay);
}

// ---------------- angle gather (streaming) -> pre (fp32) ----------------
__global__ __launch_bounds__(256) void k_angle_gather2(
    const int* __restrict__ offs, const int* __restrict__ sperm,
    const __half* __restrict__ eA, const float* __restrict__ x,
    const float* __restrict__ eps_l, float* __restrict__ pre)
{
  int w = blockIdx.x * 4 + (threadIdx.x >> 6);
  int lane = threadIdx.x & 63;
  int c = lane * 2;
  float ep = 1.f + *eps_l;
  float2 self = *(const float2*)&x[(size_t)w * DD + c];
  float ax = self.x * ep, ay = self.y * ep;
  int jb = offs[w], je = offs[w + 1];
  for (int j = jb; j < je; ++j) {
    int s = sperm[j];
    __half2 ev = *(const __half2*)&eA[(size_t)j * DD + c];
    float2 ef = __half22float2(ev);
    float2 xs2 = *(const float2*)&x[(size_t)s * DD + c];
    ax += fmaxf(xs2.x + ef.x, 0.f);
    ay += fmaxf(xs2.y + ef.y, 0.f);
  }
  *(float2*)&pre[(size_t)w * DD + c] = make_float2(ax, ay);
}

// ---------------- BN finalize ----------------
__global__ __launch_bounds__(128) void k_bn_finalize(
    const float* __restrict__ sum, const float* __restrict__ sq,
    const float* __restrict__ g, const float* __restrict__ be,
    float* __restrict__ scale, float* __restrict__ shift, float invM)
{
  int c = threadIdx.x;
  float mean = sum[c] * invM;
  float var = sq[c] * invM - mean * mean;
  float s = g[c] / sqrtf(var + 1e-5f);
  scale[c] = s;
  shift[c] = be[c] - mean * s;
}

// ======== shared GEMM / angle-embed device bodies (R8 structure) ========

// main-chain bf16x3 GEMM body: [M,128]@[128,128]+bias, A via LDS, B via LDS.
template<bool AFF, bool OUT_STATS>
__device__ __forceinline__ void gemm_body(
    int bid,
    short (*As0)[40], short (*As1)[40], short (*Bs0)[40], short (*Bs1)[40],
    float* redsum, float* redsq,
    const float* __restrict__ Af,
    const short* __restrict__ Bt0, const short* __restrict__ Bt1,
    const float* __restrict__ bias, float* __restrict__ out,
    const float* __restrict__ iscale, const float* __restrict__ ishift,
    float* __restrict__ osum, float* __restrict__ osq, int M)
{
  int tid = threadIdx.x;
  int row0 = bid * 128;
  int lane = tid & 63, wv = tid >> 6;
  int wr = (wv >> 1) * 64, wc = (wv & 1) * 64;
  int l15 = lane & 15, l4 = lane >> 4;

  if (OUT_STATS && tid < 128) { redsum[tid] = 0.f; redsq[tid] = 0.f; }

  f4v acc[4][4];
#pragma unroll
  for (int i = 0; i < 4; ++i)
#pragma unroll
    for (int j = 0; j < 4; ++j) acc[i][j] = (f4v){0.f, 0.f, 0.f, 0.f};

  for (int kc = 0; kc < 4; ++kc) {
#pragma unroll
    for (int i = 0; i < 2; ++i) {
      int vid = tid + i * 256;
      int n = vid >> 2, o = vid & 3;
      *(short8v*)&Bs0[n][o * 8] = *(const short8v*)&Bt0[n * 128 + kc * 32 + o * 8];
      *(short8v*)&Bs1[n][o * 8] = *(const short8v*)&Bt1[n * 128 + kc * 32 + o * 8];
    }
#pragma unroll
    for (int i = 0; i < 4; ++i) {
      int vid = tid + i * 256;
      int r = vid >> 3, q = vid & 7;
      int grow = row0 + r;
      float4 v = make_float4(0.f, 0.f, 0.f, 0.f);
      if (grow < M) {
        v = *(const float4*)&Af[(size_t)grow * 128 + kc * 32 + q * 4];
        if (AFF) {
          float4 sc = *(const float4*)&iscale[kc * 32 + q * 4];
          float4 sh = *(const float4*)&ishift[kc * 32 + q * 4];
          v.x = fmaxf(fmaf(v.x, sc.x, sh.x), 0.f);
          v.y = fmaxf(fmaf(v.y, sc.y, sh.y), 0.f);
          v.z = fmaxf(fmaf(v.z, sc.z, sh.z), 0.f);
          v.w = fmaxf(fmaf(v.w, sc.w, sh.w), 0.f);
        }
      }
      short a0[4], a1[4];
      split2(v.x, a0[0], a1[0]);
      split2(v.y, a0[1], a1[1]);
      split2(v.z, a0[2], a1[2]);
      split2(v.w, a0[3], a1[3]);
      *(short4*)&As0[r][q * 4] = make_short4(a0[0], a0[1], a0[2], a0[3]);
      *(short4*)&As1[r][q * 4] = make_short4(a1[0], a1[1], a1[2], a1[3]);
    }
    __syncthreads();

    short8v fa0[4], fa1[4], fb0[4], fb1[4];
#pragma unroll
    for (int mt = 0; mt < 4; ++mt) fa0[mt] = *(const short8v*)&As0[wr + mt * 16 + l15][l4 * 8];
#pragma unroll
    for (int nt = 0; nt < 4; ++nt) fb0[nt] = *(const short8v*)&Bs0[wc + nt * 16 + l15][l4 * 8];
#pragma unroll
    for (int mt = 0; mt < 4; ++mt)
#pragma unroll
      for (int nt = 0; nt < 4; ++nt)
        acc[mt][nt] = __builtin_amdgcn_mfma_f32_16x16x32_bf16(fa0[mt], fb0[nt], acc[mt][nt], 0, 0, 0);
#pragma unroll
    for (int nt = 0; nt < 4; ++nt) fb1[nt] = *(const short8v*)&Bs1[wc + nt * 16 + l15][l4 * 8];
#pragma unroll
    for (int mt = 0; mt < 4; ++mt)
#pragma unroll
      for (int nt = 0; nt < 4; ++nt)
        acc[mt][nt] = __builtin_amdgcn_mfma_f32_16x16x32_bf16(fa0[mt], fb1[nt], acc[mt][nt], 0, 0, 0);
#pragma unroll
    for (int mt = 0; mt < 4; ++mt) fa1[mt] = *(const short8v*)&As1[wr + mt * 16 + l15][l4 * 8];
#pragma unroll
    for (int mt = 0; mt < 4; ++mt)
#pragma unroll
      for (int nt = 0; nt < 4; ++nt)
        acc[mt][nt] = __builtin_amdgcn_mfma_f32_16x16x32_bf16(fa1[mt], fb0[nt], acc[mt][nt], 0, 0, 0);
    __syncthreads();
  }

  float cs[4], cq[4];
#pragma unroll
  for (int nt = 0; nt < 4; ++nt) { cs[nt] = 0.f; cq[nt] = 0.f; }
#pragma unroll
  for (int nt = 0; nt < 4; ++nt) {
    int col = wc + nt * 16 + l15;
    float bv = bias[col];
#pragma unroll
    for (int mt = 0; mt < 4; ++mt) {
#pragma unroll
      for (int j = 0; j < 4; ++j) {
        int gr = row0 + wr + mt * 16 + l4 * 4 + j;
        if (gr < M) {
          float o = acc[mt][nt][j] + bv;
          out[(size_t)gr * 128 + col] = o;
          if (OUT_STATS) { cs[nt] += o; cq[nt] += o * o; }
        }
      }
    }
  }
  if (OUT_STATS) {
#pragma unroll
    for (int nt = 0; nt < 4; ++nt) {
      int col = wc + nt * 16 + l15;
      atomicAdd(&redsum[col], cs[nt]);
      atomicAdd(&redsq[col],  cq[nt]);
    }
    __syncthreads();
    if (tid < 128) {
      atomicAdd(&osum[tid], redsum[tid]);
      atomicAdd(&osq[tid],  redsq[tid]);
    }
  }
}

// angle-embed bf16x3 body: [128 rows of perm,64]@[64,128] -> fp16 out
__device__ __forceinline__ void ang_body(
    int bid,
    short (*As0)[40], short (*As1)[40], short (*Bs0)[40], short (*Bs1)[40],
    float (*xs)[6],
    const int* __restrict__ perm, const float* __restrict__ xba,
    const short* __restrict__ Bt0, const short* __restrict__ Bt1,
    __half* __restrict__ out)
{
  int tid = threadIdx.x;
  int j0 = bid * 128;             // AA % 128 == 0
  int lane = tid & 63, wv = tid >> 6;
  int wr = (wv >> 1) * 64, wc = (wv & 1) * 64;
  int l15 = lane & 15, l4 = lane >> 4;

  if (tid < 128) {
    int a = perm[j0 + tid];
    const float* p = &xba[(size_t)a * 6];
#pragma unroll
    for (int q = 0; q < 6; ++q) xs[tid][q] = p[q];
  }
  __syncthreads();

  f4v acc[4][4];
#pragma unroll
  for (int i = 0; i < 4; ++i)
#pragma unroll
    for (int j = 0; j < 4; ++j) acc[i][j] = (f4v){0.f, 0.f, 0.f, 0.f};

  for (int kc = 0; kc < 2; ++kc) {
#pragma unroll
    for (int i = 0; i < 2; ++i) {
      int vid = tid + i * 256;
      int n = vid >> 2, o = vid & 3;
      *(short8v*)&Bs0[n][o * 8] = *(const short8v*)&Bt0[n * 64 + kc * 32 + o * 8];
      *(short8v*)&Bs1[n][o * 8] = *(const short8v*)&Bt1[n * 64 + kc * 32 + o * 8];
    }
#pragma unroll
    for (int i = 0; i < 2; ++i) {
      int vid = tid + i * 256;
      int r = vid >> 2, o = vid & 3;
      int ts = o * 8;
      short a0[8], a1[8];
      if (kc == 0) {
        float x0 = xs[r][0];
#pragma unroll
        for (int j = 0; j < 8; ++j) {
          float d = x0 - 0.1f * (float)(ts + j);
          split2(__expf(-10.f * d * d), a0[j], a1[j]);
        }
      } else {
#pragma unroll
        for (int j = 0; j < 8; ++j) {
          int t = ts + j;
          float v = (t < 5) ? xs[r][1 + t] : (t == 5 ? 1.f : 0.f);
          split2(v, a0[j], a1[j]);
        }
      }
      short8v v0 = {a0[0], a0[1], a0[2], a0[3], a0[4], a0[5], a0[6], a0[7]};
      short8v v1 = {a1[0], a1[1], a1[2], a1[3], a1[4], a1[5], a1[6], a1[7]};
      *(short8v*)&As0[r][ts] = v0;
      *(short8v*)&As1[r][ts] = v1;
    }
    __syncthreads();

    short8v fa0[4], fa1[4], fb0[4], fb1[4];
#pragma unroll
    for (int mt = 0; mt < 4; ++mt) fa0[mt] = *(const short8v*)&As0[wr + mt * 16 + l15][l4 * 8];
#pragma unroll
    for (int nt = 0; nt < 4; ++nt) fb0[nt] = *(const short8v*)&Bs0[wc + nt * 16 + l15][l4 * 8];
#pragma unroll
    for (int mt = 0; mt < 4; ++mt)
#pragma unroll
      for (int nt = 0; nt < 4; ++nt)
        acc[mt][nt] = __builtin_amdgcn_mfma_f32_16x16x32_bf16(fa0[mt], fb0[nt], acc[mt][nt], 0, 0, 0);
#pragma unroll
    for (int nt = 0; nt < 4; ++nt) fb1[nt] = *(const short8v*)&Bs1[wc + nt * 16 + l15][l4 * 8];
#pragma unroll
    for (int mt = 0; mt < 4; ++mt)
#pragma unroll
      for (int nt = 0; nt < 4; ++nt)
        acc[mt][nt] = __builtin_amdgcn_mfma_f32_16x16x32_bf16(fa0[mt], fb1[nt], acc[mt][nt], 0, 0, 0);
#pragma unroll
    for (int mt = 0; mt < 4; ++mt) fa1[mt] = *(const short8v*)&As1[wr + mt * 16 + l15][l4 * 8];
#pragma unroll
    for (int mt = 0; mt < 4; ++mt)
#pragma unroll
      for (int nt = 0; nt < 4; ++nt)
        acc[mt][nt] = __builtin_amdgcn_mfma_f32_16x16x32_bf16(fa1[mt], fb0[nt], acc[mt][nt], 0, 0, 0);
    __syncthreads();
  }

#pragma unroll
  for (int nt = 0; nt < 4; ++nt) {
    int col = wc + nt * 16 + l15;
#pragma unroll
    for (int mt = 0; mt < 4; ++mt) {
#pragma unroll
      for (int j = 0; j < 4; ++j) {
        int gj = j0 + wr + mt * 16 + l4 * 4 + j;
        out[(size_t)gj * DD + col] = __float2half(acc[mt][nt][j]);
      }
    }
  }
}

// ---------------- standalone GEMM (R8 structure) ----------------
template<bool AFF, bool OUT_STATS>
__global__ __launch_bounds__(256) void k_gemm_mfma(
    const float* __restrict__ Af,
    const short* __restrict__ Bt0, const short* __restrict__ Bt1,
    const float* __restrict__ bias, float* __restrict__ out,
    const float* __restrict__ iscale, const float* __restrict__ ishift,
    float* __restrict__ osum, float* __restrict__ osq, int M)
{
  __shared__ short As0[128][40], As1[128][40];
  __shared__ short Bs0[128][40], Bs1[128][40];
  __shared__ float redsum[128], redsq[128];
  gemm_body<AFF, OUT_STATS>(blockIdx.x, As0, As1, Bs0, Bs1, redsum, redsq,
                            Af, Bt0, Bt1, bias, out, iscale, ishift, osum, osq, M);
}

// ---------------- fused: atom-G1 GEMM (blocks < gemmBlocks) + angle embed ----
// The two are independent: G1 reads preB/writes T; ang reads xba/writes eAh.
// Concatenated grid co-schedules them, filling the latency slack of each.
__global__ __launch_bounds__(256) void k_g1_ang(
    const float* __restrict__ Af,
    const short* __restrict__ Bt0, const short* __restrict__ Bt1,
    const float* __restrict__ bias, float* __restrict__ out,
    float* __restrict__ osum, float* __restrict__ osq, int M, int gemmBlocks,
    const int* __restrict__ perm, const float* __restrict__ xba,
    const short* __restrict__ At0, const short* __restrict__ At1,
    __half* __restrict__ eout)
{
  __shared__ short As0[128][40], As1[128][40];
  __shared__ short Bs0[128][40], Bs1[128][40];
  __shared__ float redsum[128], redsq[128];
  __shared__ float xs[128][6];
  int bid = blockIdx.x;
  if (bid < gemmBlocks) {
    gemm_body<false, true>(bid, As0, As1, Bs0, Bs1, redsum, redsq,
                           Af, Bt0, Bt1, bias, out, nullptr, nullptr, osum, osq, M);
  } else {
    ang_body(bid - gemmBlocks, As0, As1, Bs0, Bs1, xs, perm, xba, At0, At1, eout);
  }
}

// ---------------- bond embed as MFMA bf16x3 GEMM [E,320]@[320,128] ----------------
__global__ __launch_bounds__(256) void k_bond_mfma(
    const float* __restrict__ xf, const int* __restrict__ eai,
    const short* __restrict__ Bt0, const short* __restrict__ Bt1,
    float* __restrict__ out)
{
  __shared__ short As0[128][40], As1[128][40];
  __shared__ short Bs0[128][40], Bs1[128][40];
  __shared__ float xfs[128][8];
  __shared__ int   iis[128][3];
  int tid = threadIdx.x;
  int e0 = blockIdx.x * 128;
  int lane = tid & 63, wv = tid >> 6;
  int wr = (wv >> 1) * 64, wc = (wv & 1) * 64;
  int l15 = lane & 15, l4 = lane >> 4;

  {
    int e = tid >> 1, f4i = (tid & 1) * 4;
    float4 v = make_float4(1e15f, 1e15f, 1e15f, 1e15f);
    if (e0 + e < EE) v = *(const float4*)&xf[(size_t)(e0 + e) * 8 + f4i];
    xfs[e][f4i] = v.x; xfs[e][f4i + 1] = v.y; xfs[e][f4i + 2] = v.z; xfs[e][f4i + 3] = v.w;
  }
  if (tid < 128) {
    int e = tid;
    if (e0 + e < EE) {
      iis[e][0] = eai[(size_t)(e0 + e) * 3];
      iis[e][1] = eai[(size_t)(e0 + e) * 3 + 1];
      iis[e][2] = eai[(size_t)(e0 + e) * 3 + 2];
    } else { iis[e][0] = -1; iis[e][1] = -1; iis[e][2] = -1; }
  }
  __syncthreads();

  f4v acc[4][4];
#pragma unroll
  for (int i = 0; i < 4; ++i)
#pragma unroll
    for (int j = 0; j < 4; ++j) acc[i][j] = (f4v){0.f, 0.f, 0.f, 0.f};

  for (int kc = 0; kc < 10; ++kc) {
#pragma unroll
    for (int i = 0; i < 2; ++i) {
      int vid = tid + i * 256;
      int n = vid >> 2, o = vid & 3;
      *(short8v*)&Bs0[n][o * 8] = *(const short8v*)&Bt0[n * 320 + kc * 32 + o * 8];
      *(short8v*)&Bs1[n][o * 8] = *(const short8v*)&Bt1[n * 320 + kc * 32 + o * 8];
    }
#pragma unroll
    for (int i = 0; i < 2; ++i) {
      int vid = tid + i * 256;
      int e = vid >> 2, o = vid & 3;
      int ts = o * 8;
      if (kc < 8) {
        float x = xfs[e][kc];
        float gam = c_bf_gam[kc], st = c_bf_start[kc], sp = c_bf_step[kc];
        int cnt = c_bf_cnt[kc];
        short a0[8], a1[8];
#pragma unroll
        for (int j = 0; j < 8; ++j) {
          int t = ts + j;
          float dx = x - (st + sp * (float)t);
          float v = (t < cnt) ? __expf(-gam * dx * dx) : 0.f;
          split2(v, a0[j], a1[j]);
        }
        short8v v0 = {a0[0], a0[1], a0[2], a0[3], a0[4], a0[5], a0[6], a0[7]};
        short8v v1 = {a1[0], a1[1], a1[2], a1[3], a1[4], a1[5], a1[6], a1[7]};
        *(short8v*)&As0[e][ts] = v0;
        *(short8v*)&As1[e][ts] = v1;
      } else {
        short a0[8];
        if (kc == 8) {
          int i0 = iis[e][0], i1 = iis[e][1];
#pragma unroll
          for (int j = 0; j < 8; ++j) {
            int t = ts + j;
            float v = (t < 12) ? (t == i0 ? 1.f : 0.f)
                    : (t < 24) ? ((t - 12) == i1 ? 1.f : 0.f) : 0.f;
            a0[j] = f2bf(v);
          }
        } else {
          int i2 = iis[e][2];
#pragma unroll
          for (int j = 0; j < 8; ++j) {
            int t = ts + j;
            float v = (t < 12) ? (t == i2 ? 1.f : 0.f) : (t == 12 ? 1.f : 0.f);
            a0[j] = f2bf(v);
          }
        }
        short8v v0 = {a0[0], a0[1], a0[2], a0[3], a0[4], a0[5], a0[6], a0[7]};
        *(short8v*)&As0[e][ts] = v0;
      }
    }
    __syncthreads();

    short8v fa0[4], fa1[4], fb0[4], fb1[4];
#pragma unroll
    for (int mt = 0; mt < 4; ++mt) fa0[mt] = *(const short8v*)&As0[wr + mt * 16 + l15][l4 * 8];
#pragma unroll
    for (int nt = 0; nt < 4; ++nt) fb0[nt] = *(const short8v*)&Bs0[wc + nt * 16 + l15][l4 * 8];
#pragma unroll
    for (int mt = 0; mt < 4; ++mt)
#pragma unroll
      for (int nt = 0; nt < 4; ++nt)
        acc[mt][nt] = __builtin_amdgcn_mfma_f32_16x16x32_bf16(fa0[mt], fb0[nt], acc[mt][nt], 0, 0, 0);
#pragma unroll
    for (int nt = 0; nt < 4; ++nt) fb1[nt] = *(const short8v*)&Bs1[wc + nt * 16 + l15][l4 * 8];
#pragma unroll
    for (int mt = 0; mt < 4; ++mt)
#pragma unroll
      for (int nt = 0; nt < 4; ++nt)
        acc[mt][nt] = __builtin_amdgcn_mfma_f32_16x16x32_bf16(fa0[mt], fb1[nt], acc[mt][nt], 0, 0, 0);
    if (kc < 8) {
#pragma unroll
      for (int mt = 0; mt < 4; ++mt) fa1[mt] = *(const short8v*)&As1[wr + mt * 16 + l15][l4 * 8];
#pragma unroll
      for (int mt = 0; mt < 4; ++mt)
#pragma unroll
        for (int nt = 0; nt < 4; ++nt)
          acc[mt][nt] = __builtin_amdgcn_mfma_f32_16x16x32_bf16(fa1[mt], fb0[nt], acc[mt][nt], 0, 0, 0);
    }
    __syncthreads();
  }

#pragma unroll
  for (int nt = 0; nt < 4; ++nt) {
    int col = wc + nt * 16 + l15;
#pragma unroll
    for (int mt = 0; mt < 4; ++mt) {
#pragma unroll
      for (int j = 0; j < 4; ++j) {
        int ge = e0 + wr + mt * 16 + l4 * 4 + j;
        if (ge < EE) out[(size_t)ge * 128 + col] = acc[mt][nt][j];
      }
    }
  }
}

extern "C" void kernel_launch(void* const* d_in, const int* in_sizes, int n_in,
                              void* d_out, int out_size, void* d_ws, size_t ws_size,
                              hipStream_t stream)
{
  (void)in_sizes; (void)n_in; (void)out_size; (void)ws_size;
  const int*   x_atom = (const int*)  d_in[0];
  const int*   ei     = (const int*)  d_in[1];
  const int*   eai    = (const int*)  d_in[2];
  const int*   eib    = (const int*)  d_in[3];
  const float* xf     = (const float*)d_in[4];
  const float* xba    = (const float*)d_in[5];
  const float* atab   = (const float*)d_in[6];
  const float* btab   = (const float*)d_in[7];
  const float* bfW    = (const float*)d_in[8];
  const float* bfb    = (const float*)d_in[9];
  const float* Wang   = (const float*)d_in[10];
  const float* bang   = (const float*)d_in[11];
  const float* Wrest  = (const float*)d_in[12];
  const float* brest  = (const float*)d_in[13];
  const float* eps_a  = (const float*)d_in[14];
  const float* W1_a   = (const float*)d_in[15];
  const float* b1_a   = (const float*)d_in[16];
  const float* bng_a  = (const float*)d_in[17];
  const float* bnb_a  = (const float*)d_in[18];
  const float* W2_a   = (const float*)d_in[19];
  const float* b2_a   = (const float*)d_in[20];
  const float* eps_g  = (const float*)d_in[21];
  const float* W1_g   = (const float*)d_in[22];
  const float* b1_g   = (const float*)d_in[23];
  const float* bng_g  = (const float*)d_in[24];
  const float* bnb_g  = (const float*)d_in[25];
  const float* W2_g   = (const float*)d_in[26];
  const float* b2_g   = (const float*)d_in[27];
  const float* obng_a = (const float*)d_in[28];
  const float* obnb_a = (const float*)d_in[29];
  const float* obng_b = (const float*)d_in[30];
  const float* obnb_b = (const float*)d_in[31];

  float* out_a = (float*)d_out;
  float* out_b = out_a + (size_t)NN * DD;
  char* base = (char*)d_ws;
  const size_t ED = (size_t)EE * DD, ND = (size_t)NN * DD;

  float* preB  = (float*)base;                 base += ED * 4;          // 102.4 MB
  float* T     = (float*)base;                 base += ED * 4;          // 102.4 MB
  float* hB0   = (float*)base;                 base += ED * 4;          // 102.4 MB
  float* hA0   = (float*)base;                 base += ND * 4;          // 51.2 MB
  float* stats = (float*)base;                 base += 1280 * 4;
  float* sum1 = stats,        *sq1 = stats + 128;
  float* sum2 = stats + 256,  *sq2 = stats + 384;
  float* sc1  = stats + 512,  *sh1 = stats + 640;
  float* oscH = stats + 768,  *oshH = stats + 896;
  float* oscB = stats + 1024, *oshB = stats + 1152;
  int* offsA = (int*)base;                     base += (NN + 1) * 4;
  int* permA = (int*)base;                     base += (size_t)EE * 4;
  int* offsB = (int*)base;                     base += (EE + 1) * 4;
  int* permB = (int*)base;                     base += (size_t)AA * 4;
  int* curA  = (int*)base;                     base += (size_t)NN * 4;
  int* curB  = (int*)base;                     base += (size_t)EE * 4;
  short* Wt0 = (short*)base;                   base += 20 * 16384 * 2;  // [4 grp][5][n][k]
  short* Wt1 = (short*)base;                   base += 20 * 16384 * 2;
  short* Bt0 = (short*)base;                   base += 6 * 40960 * 2;   // [6][n][320]
  short* Bt1 = (short*)base;                   base += 6 * 40960 * 2;
  base = (char*)(((uintptr_t)base + 15) & ~(uintptr_t)15);
  short* Ang0 = (short*)base;                  base += 5 * 8192 * 2;    // [5][n=128][k=64]
  short* Ang1 = (short*)base;                  base += 5 * 8192 * 2;
  int* spermB = (int*)base;                    base += (size_t)AA * 4;  // 1.6 MB
  int* bsumA  = (int*)base;                    base += 256 * 4;
  int* bsumB  = (int*)base;                    base += 256 * 4;

  // ---- prep: weight transpose/split ----
  k_prep_w<<<5 * 128, 128, 0, stream>>>(W1_a, Wt0,              Wt1);
  k_prep_w<<<5 * 128, 128, 0, stream>>>(W2_a, Wt0 + 5 * 16384,  Wt1 + 5 * 16384);
  k_prep_w<<<5 * 128, 128, 0, stream>>>(W1_g, Wt0 + 10 * 16384, Wt1 + 10 * 16384);
  k_prep_w<<<5 * 128, 128, 0, stream>>>(W2_g, Wt0 + 15 * 16384, Wt1 + 15 * 16384);
  k_prep_bond<<<6 * 128, 320, 0, stream>>>(bfW, btab, bfb, Bt0, Bt1);
  k_prep_ang<<<5 * 128, 64, 0, stream>>>(Wang, bang, Wrest, brest, Ang0, Ang1);

  // ---- CSR build (parallel 3-phase scan) ----
  hipMemsetAsync(curA, 0, NN * sizeof(int), stream);
  hipMemsetAsync(curB, 0, EE * sizeof(int), stream);
  k_count<<<(EE + 255) / 256, 256, 0, stream>>>(ei + EE, curA, EE);
  k_count<<<(AA + 255) / 256, 256, 0, stream>>>(eib + AA, curB, AA);
  const int nbA = (NN + 1023) / 1024, nbB = (EE + 1023) / 1024;
  k_scan1<<<nbA, 1024, 0, stream>>>(curA, offsA, bsumA, NN);
  k_scan1<<<nbB, 1024, 0, stream>>>(curB, offsB, bsumB, EE);
  k_scan2<<<1, 256, 0, stream>>>(bsumA, nbA);
  k_scan2<<<1, 256, 0, stream>>>(bsumB, nbB);
  k_scan3<<<nbA, 1024, 0, stream>>>(offsA, bsumA, curA, NN, EE);
  k_scan3<<<nbB, 1024, 0, stream>>>(offsB, bsumB, curB, EE, AA);
  k_fill<<<(EE + 255) / 256, 256, 0, stream>>>(ei + EE, curA, permA, EE);
  k_fill<<<(AA + 255) / 256, 256, 0, stream>>>(eib + AA, curB, permB, AA);
  k_sperm<<<(AA + 255) / 256, 256, 0, stream>>>(permB, eib, spermB, AA);

  // ---- initial embeddings ----
  k_atom_embed<<<NN, 128, 0, stream>>>(x_atom, atab, hA0);
  const int gB = (EE + 127) / 128;
  k_bond_mfma<<<gB, 256, 0, stream>>>(xf, eai, Bt0, Bt1, hB0);

  const int gA = (NN + 127) / 128;
  float* hA_cur = hA0;
  float* hB_cur = hB0;
  for (int l = 0; l < LL; ++l) {
    float* hA_nxt = (l & 1) ? hA0 : out_a;
    float* hB_nxt = (l & 1) ? hB0 : out_b;
    const bool obn = (l < LL - 1);
    size_t o1a = (size_t)l * 16384, o2a = (size_t)(5 + l) * 16384;
    size_t o1g = (size_t)(10 + l) * 16384, o2g = (size_t)(15 + l) * 16384;

    // ---- atom GIN conv ----
    if (l == 0)
      k_atom_gather<false><<<NN / 4, 256, 0, stream>>>(
          offsA, permA, ei, hA_cur, hB_cur, nullptr, nullptr, nullptr, nullptr,
          eps_a + l, preB);
    else
      k_atom_gather<true><<<NN / 4, 256, 0, stream>>>(
          offsA, permA, ei, hA_cur, hB_cur, oscH, oshH, oscB, oshB,
          eps_a + l, preB);
    // hB_cur is dead after atom_gather: reuse its 102.4 MB as the fp16 angle
    // embedding buffer (AA*128*2B == EE*128*4B).
    __half* eAh = (__half*)hB_cur;
    hipMemsetAsync(stats, 0, 512 * sizeof(float), stream);
    // fused: atom-G1 GEMM (preB@W1 -> T, stats) + angle embed (xba -> eAh)
    k_g1_ang<<<gA + AA / 128, 256, 0, stream>>>(
        preB, Wt0 + o1a, Wt1 + o1a, b1_a + l * DD, T, sum1, sq1, NN, gA,
        permB, xba, Ang0 + (size_t)l * 8192, Ang1 + (size_t)l * 8192, eAh);
    k_bn_finalize<<<1, 128, 0, stream>>>(sum1, sq1, bng_a + l * DD, bnb_a + l * DD, sc1, sh1, 1.f / NN);
    if (obn) {
      k_gemm_mfma<true, true><<<gA, 256, 0, stream>>>(
          T, Wt0 + o2a, Wt1 + o2a,
          b2_a + l * DD, hA_nxt, sc1, sh1, sum2, sq2, NN);
      k_bn_finalize<<<1, 128, 0, stream>>>(sum2, sq2, obng_a + l * DD, obnb_a + l * DD, oscH, oshH, 1.f / NN);
    } else {
      k_gemm_mfma<true, false><<<gA, 256, 0, stream>>>(
          T, Wt0 + o2a, Wt1 + o2a,
          b2_a + l * DD, hA_nxt, sc1, sh1, nullptr, nullptr, NN);
    }

    // ---- bond GIN conv ----
    k_bond_mfma<<<gB, 256, 0, stream>>>(
        xf, eai, Bt0 + (size_t)(l + 1) * 40960, Bt1 + (size_t)(l + 1) * 40960, T);
    k_angle_gather2<<<EE / 4, 256, 0, stream>>>(
        offsB, spermB, eAh, T, eps_g + l, preB);
    hipMemsetAsync(stats, 0, 512 * sizeof(float), stream);
    k_gemm_mfma<false, true><<<gB, 256, 0, stream>>>(
        preB, Wt0 + o1g, Wt1 + o1g,
        b1_g + l * DD, T, nullptr, nullptr, sum1, sq1, EE);
    k_bn_finalize<<<1, 128, 0, stream>>>(sum1, sq1, bng_g + l * DD, bnb_g + l * DD, sc1, sh1, 1.f / EE);
    if (obn) {
      k_gemm_mfma<true, true><<<gB, 256, 0, stream>>>(
          T, Wt0 + o2g, Wt1 + o2g,
          b2_g + l * DD, hB_nxt, sc1, sh1, sum2, sq2, EE);
      k_bn_finalize<<<1, 128, 0, stream>>>(sum2, sq2, obng_b + l * DD, obnb_b + l * DD, oscB, oshB, 1.f / EE);
    } else {
      k_gemm_mfma<true, false><<<gB, 256, 0, stream>>>(
          T, Wt0 + o2g, Wt1 + o2g,
          b2_g + l * DD, hB_nxt, sc1, sh1, nullptr, nullptr, EE);
    }

    hA_cur = hA_nxt;
    hB_cur = hB_nxt;
  }
}